// Round 7
// baseline (150.384 us; speedup 1.0000x reference)
//
#include <hip/hip_runtime.h>

#define BB 32
#define HH 512
#define WW 512
#define CC 3
#define KK 16
#define NE 19          // K + 3
#define KNL 16         // nonlinear kernel terms
#define NN (HH * WW)   // 262144
#define NCF (BB * 2 * NE) // 1216 coeff floats
#define NPB (NN / 256) // 1024 pixel-groups of 256
#define STEPS (BB / 2) // 16 batches per block

// Pre-kernel: coeff[b][p][e] = sum_k (src[p][k] + off[b][p*K+k]) * L_inv[e][3+k]
__global__ __launch_bounds__(256) void coeff_kernel(
    const float* __restrict__ dest_offsets, // (B, 2K)
    const float* __restrict__ L_inv,        // (NE, NE)
    const float* __restrict__ src_pts,      // (2, K)
    float* __restrict__ cf)                 // (B, 2, NE)
{
    const int i = blockIdx.x * 256 + threadIdx.x;
    if (i >= NCF) return;
    const int b = i / (2 * NE);
    const int rem = i - b * (2 * NE);
    const int p = rem / NE;
    const int e = rem - p * NE;
    float acc = 0.0f;
    #pragma unroll
    for (int k = 0; k < KK; ++k) {
        const float d = src_pts[p * KK + k] + dest_offsets[b * 2 * KK + p * KK + k];
        acc = fmaf(d, L_inv[e * NE + 3 + k], acc);
    }
    cf[i] = acc;
}

// Persistent pixel-group kernel: block w owns pixel-group (w & 1023) and
// marches over batches b = (w>>10) + 2g, g = 0..15. All 2048 blocks are
// co-resident (8 blocks/CU at <=64 VGPR), so the chip processes ~2 batches
// at any instant -> gathers hit a ~6 MB L2/L3-hot image working set, and
// each thread's right_mat column is loaded once and reused for 16 batches.
__global__ __launch_bounds__(256, 8) void tps_kernel(
    const float* __restrict__ image,        // (B,H,W,C)
    const float* __restrict__ right_mat,    // (NE, N)
    const float* __restrict__ cf,           // (B, 2, NE) in d_ws
    float* __restrict__ out)                // (B,H,W,C)
{
    const int w = blockIdx.x;
    const int pblk = w & (NPB - 1);
    const int bpar = w >> 10;               // batch parity: 0 or 1
    const int tid = threadIdx.x;
    const int n = pblk * 256 + tid;

    // right_mat rows 0..2 are [1; x_t; y_t] — compute instead of load.
    const int col = n & (WW - 1);
    const int row = n >> 9;
    const float xt = fmaf((float)col, 2.0f / 511.0f, -1.0f);
    const float yt = fmaf((float)row, 2.0f / 511.0f, -1.0f);

    // Nonlinear right_mat rows: loaded ONCE, reused for all 16 batches.
    float rm[KNL];
    #pragma unroll
    for (int e = 0; e < KNL; ++e)
        rm[e] = right_mat[(size_t)(e + 3) * NN + n];

    #pragma unroll 1
    for (int g = 0; g < STEPS; ++g) {
        const int b = bpar + 2 * g;

        // Block-uniform coefficient address -> scalar loads.
        const float* __restrict__ c0 = cf + (size_t)b * 2 * NE; // p = 0 (x)
        const float* __restrict__ c1 = c0 + NE;                 // p = 1 (y)

        float tx = fmaf(c0[1], xt, c0[0]);
        float ty = fmaf(c1[1], xt, c1[0]);
        tx = fmaf(c0[2], yt, tx);
        ty = fmaf(c1[2], yt, ty);
        #pragma unroll
        for (int e = 0; e < KNL; ++e) {
            tx = fmaf(c0[3 + e], rm[e], tx);
            ty = fmaf(c1[3 + e], rm[e], ty);
        }

        const float x = 0.5f * (tx + 1.0f) * (float)WW;
        const float y = 0.5f * (ty + 1.0f) * (float)HH;

        int x0 = (int)x;   // trunc toward zero, matches astype(int32)
        int x1 = x0 + 1;
        int y0 = (int)y;
        int y1 = y0 + 1;
        x0 = min(max(x0, 0), WW - 1);
        x1 = min(max(x1, 0), WW - 1);
        y0 = min(max(y0, 0), HH - 1);
        y1 = min(max(y1, 0), HH - 1);

        const float x0f = (float)x0, x1f = (float)x1;
        const float y0f = (float)y0, y1f = (float)y1;
        const float wa = (x1f - x) * (y1f - y);
        const float wb = (x1f - x) * (y - y0f);
        const float wc = (x - x0f) * (y1f - y);
        const float wd = (x - x0f) * (y - y0f);

        // Row-pair gather: 6 contiguous floats per row from xs = min(x0, W-2).
        const int xs = min(x0, WW - 2);
        const bool hi_a = (x0 > xs);
        const bool hi_c = (x1 > xs);

        const float* __restrict__ img = image + (size_t)b * NN * CC;
        const float* rowA = img + ((size_t)y0 * WW + xs) * CC;
        const float* rowB = img + ((size_t)y1 * WW + xs) * CC;
        float la[6], lb[6];
        __builtin_memcpy(la, rowA, 6 * sizeof(float));
        __builtin_memcpy(lb, rowB, 6 * sizeof(float));

        float res[CC];
        #pragma unroll
        for (int c = 0; c < CC; ++c) {
            const float pa = hi_a ? la[c + 3] : la[c];
            const float pc = hi_c ? la[c + 3] : la[c];
            const float pb = hi_a ? lb[c + 3] : lb[c];
            const float pd = hi_c ? lb[c + 3] : lb[c];
            res[c] = wa * pa + wb * pb + wc * pc + wd * pd;
        }
        float* __restrict__ o = out + ((size_t)b * NN + n) * CC;
        __builtin_memcpy(o, res, CC * sizeof(float));
    }
}

extern "C" void kernel_launch(void* const* d_in, const int* in_sizes, int n_in,
                              void* d_out, int out_size, void* d_ws, size_t ws_size,
                              hipStream_t stream) {
    const float* image        = (const float*)d_in[0];
    const float* dest_offsets = (const float*)d_in[1];
    const float* right_mat    = (const float*)d_in[2];
    const float* L_inv        = (const float*)d_in[3];
    const float* src_pts      = (const float*)d_in[4];
    float* out = (float*)d_out;
    float* cf  = (float*)d_ws;   // 1216 floats

    hipLaunchKernelGGL(coeff_kernel, dim3((NCF + 255) / 256), dim3(256), 0, stream,
                       dest_offsets, L_inv, src_pts, cf);
    hipLaunchKernelGGL(tps_kernel, dim3(2 * NPB), dim3(256), 0, stream,
                       image, right_mat, cf, out);
}

// Round 8
// 97.342 us; speedup vs baseline: 1.5449x; 1.5449x over previous
//
#include <hip/hip_runtime.h>

#define BB 32
#define HH 512
#define WW 512
#define CC 3
#define KK 16
#define NE 19        // K + 3
#define NN (HH * WW) // 262144
#define BPB 4        // batches per block
#define NCOEFF (BPB * 2 * NE) // 152

__global__ __launch_bounds__(256, 4) void tps_kernel(
    const float* __restrict__ image,        // (B,H,W,C)
    const float* __restrict__ dest_offsets, // (B, 2K)
    const float* __restrict__ right_mat,    // (NE, N)
    const float* __restrict__ L_inv,        // (NE, NE)
    const float* __restrict__ src_pts,      // (2, K)
    float* __restrict__ out)                // (B,H,W,C)
{
    __shared__ float s_coeff[BPB][2][NE];
    const int tid = threadIdx.x;
    const int b0 = blockIdx.y * BPB;

    // TPS coefficients for this block's batch group:
    // coeff[bb][p][e] = sum_k (src[p][k] + off[b][p*K+k]) * L_inv[e][3+k]
    if (tid < NCOEFF) {
        const int bb = tid / (2 * NE);
        const int rem = tid - bb * (2 * NE);
        const int p = rem / NE;
        const int e = rem - p * NE;
        const int b = b0 + bb;
        float acc = 0.0f;
        #pragma unroll
        for (int k = 0; k < KK; ++k) {
            const float d = src_pts[p * KK + k] + dest_offsets[b * 2 * KK + p * KK + k];
            acc = fmaf(d, L_inv[e * NE + 3 + k], acc);
        }
        s_coeff[bb][p][e] = acc;
    }
    __syncthreads();

    const int n = blockIdx.x * 256 + tid;

    // This pixel's right_mat column (each row-read coalesced across lanes).
    float rm[NE];
    #pragma unroll
    for (int e = 0; e < NE; ++e)
        rm[e] = right_mat[(size_t)e * NN + n];

    float* __restrict__ o = out + (size_t)b0 * NN * CC + (size_t)n * CC;

    #pragma unroll
    for (int bb = 0; bb < BPB; ++bb) {
        float tx = 0.0f, ty = 0.0f;
        #pragma unroll
        for (int e = 0; e < NE; ++e) {
            tx = fmaf(s_coeff[bb][0][e], rm[e], tx);
            ty = fmaf(s_coeff[bb][1][e], rm[e], ty);
        }
        const float x = 0.5f * (tx + 1.0f) * (float)WW;
        const float y = 0.5f * (ty + 1.0f) * (float)HH;

        int x0 = (int)x;   // trunc toward zero, matches astype(int32)
        int x1 = x0 + 1;
        int y0 = (int)y;
        int y1 = y0 + 1;
        x0 = min(max(x0, 0), WW - 1);
        x1 = min(max(x1, 0), WW - 1);
        y0 = min(max(y0, 0), HH - 1);
        y1 = min(max(y1, 0), HH - 1);

        const float x0f = (float)x0, x1f = (float)x1;
        const float y0f = (float)y0, y1f = (float)y1;
        const float wa = (x1f - x) * (y1f - y);
        const float wb = (x1f - x) * (y - y0f);
        const float wc = (x - x0f) * (y1f - y);
        const float wd = (x - x0f) * (y - y0f);

        // Row-pair gather: 6 contiguous floats per row from xs = min(x0, W-2).
        const int xs = min(x0, WW - 2);
        const bool hi_a = (x0 > xs);
        const bool hi_c = (x1 > xs);

        const float* img = image + (size_t)(b0 + bb) * NN * CC;
        const float* rowA = img + ((size_t)y0 * WW + xs) * CC;
        const float* rowB = img + ((size_t)y1 * WW + xs) * CC;
        float la[6], lb[6];
        __builtin_memcpy(la, rowA, 6 * sizeof(float));
        __builtin_memcpy(lb, rowB, 6 * sizeof(float));

        float res[CC];
        #pragma unroll
        for (int c = 0; c < CC; ++c) {
            const float pa = hi_a ? la[c + 3] : la[c];
            const float pc = hi_c ? la[c + 3] : la[c];
            const float pb = hi_a ? lb[c + 3] : lb[c];
            const float pd = hi_c ? lb[c + 3] : lb[c];
            res[c] = wa * pa + wb * pb + wc * pc + wd * pd;
        }

        // Output is write-once / never re-read: bypass L2/L3 allocation so the
        // image + right_mat stay L3-resident and gathers stop missing to HBM.
        float* dst = o + (size_t)bb * NN * CC;
        __builtin_nontemporal_store(res[0], dst + 0);
        __builtin_nontemporal_store(res[1], dst + 1);
        __builtin_nontemporal_store(res[2], dst + 2);
    }
}

extern "C" void kernel_launch(void* const* d_in, const int* in_sizes, int n_in,
                              void* d_out, int out_size, void* d_ws, size_t ws_size,
                              hipStream_t stream) {
    const float* image        = (const float*)d_in[0];
    const float* dest_offsets = (const float*)d_in[1];
    const float* right_mat    = (const float*)d_in[2];
    const float* L_inv        = (const float*)d_in[3];
    const float* src_pts      = (const float*)d_in[4];
    float* out = (float*)d_out;

    dim3 grid(NN / 256, BB / BPB);
    dim3 block(256);
    hipLaunchKernelGGL(tps_kernel, grid, block, 0, stream,
                       image, dest_offsets, right_mat, L_inv, src_pts, out);
}

// Round 9
// 94.946 us; speedup vs baseline: 1.5839x; 1.0252x over previous
//
#include <hip/hip_runtime.h>

#define BB 32
#define HH 512
#define WW 512
#define CC 3
#define KK 16
#define NE 19        // K + 3
#define NN (HH * WW) // 262144
#define BPB 4        // batches per block
#define NCOEFF (BPB * 2 * NE) // 152

typedef float v4f __attribute__((ext_vector_type(4)));
typedef float v2f __attribute__((ext_vector_type(2)));

// Issue a 24B row-pair load (6 floats) as dwordx4 + dwordx2, uninterruptible
// by the IR-level sinking that defeated rounds 3/4/5 (volatile asm preserves
// issue order; results land in q4/q2 and stay in flight).
#define ISSUE_ROW(q4, q2, addr)                                              \
    asm volatile("global_load_dwordx4 %0, %2, off\n\t"                       \
                 "global_load_dwordx2 %1, %2, off offset:16"                 \
                 : "=&v"(q4), "=&v"(q2)                                      \
                 : "v"(addr))

// Wait until this batch's 4 loads have returned (vmcnt retires in issue
// order), tying the registers so consumers can't be scheduled above it.
#define WAIT_BATCH(NW, A4, A2, B4, B2)                                       \
    asm volatile("s_waitcnt vmcnt(" #NW ")"                                  \
                 : "+v"(A4), "+v"(A2), "+v"(B4), "+v"(B2))

__global__ __launch_bounds__(256, 4) void tps_kernel(
    const float* __restrict__ image,        // (B,H,W,C)
    const float* __restrict__ dest_offsets, // (B, 2K)
    const float* __restrict__ right_mat,    // (NE, N)
    const float* __restrict__ L_inv,        // (NE, NE)
    const float* __restrict__ src_pts,      // (2, K)
    float* __restrict__ out)                // (B,H,W,C)
{
    __shared__ float s_coeff[BPB][2][NE];
    const int tid = threadIdx.x;
    const int b0 = blockIdx.y * BPB;

    // TPS coefficients for this block's batch group:
    // coeff[bb][p][e] = sum_k (src[p][k] + off[b][p*K+k]) * L_inv[e][3+k]
    if (tid < NCOEFF) {
        const int bb = tid / (2 * NE);
        const int rem = tid - bb * (2 * NE);
        const int p = rem / NE;
        const int e = rem - p * NE;
        const int b = b0 + bb;
        float acc = 0.0f;
        #pragma unroll
        for (int k = 0; k < KK; ++k) {
            const float d = src_pts[p * KK + k] + dest_offsets[b * 2 * KK + p * KK + k];
            acc = fmaf(d, L_inv[e * NE + 3 + k], acc);
        }
        s_coeff[bb][p][e] = acc;
    }
    __syncthreads();

    const int n = blockIdx.x * 256 + tid;

    // This pixel's right_mat column (each row-read coalesced across lanes).
    float rm[NE];
    #pragma unroll
    for (int e = 0; e < NE; ++e)
        rm[e] = right_mat[(size_t)e * NN + n];

    // Phase A: coords + weights for all batches; ISSUE all 16 gathers.
    float wa[BPB], wb[BPB], wc[BPB], wd[BPB];
    bool hi_a[BPB], hi_c[BPB];
    v4f a4[BPB], b4[BPB];
    v2f a2[BPB], b2[BPB];

    #pragma unroll
    for (int bb = 0; bb < BPB; ++bb) {
        float tx = 0.0f, ty = 0.0f;
        #pragma unroll
        for (int e = 0; e < NE; ++e) {
            tx = fmaf(s_coeff[bb][0][e], rm[e], tx);
            ty = fmaf(s_coeff[bb][1][e], rm[e], ty);
        }
        const float x = 0.5f * (tx + 1.0f) * (float)WW;
        const float y = 0.5f * (ty + 1.0f) * (float)HH;

        int x0 = (int)x;   // trunc toward zero, matches astype(int32)
        int x1 = x0 + 1;
        int y0 = (int)y;
        int y1 = y0 + 1;
        x0 = min(max(x0, 0), WW - 1);
        x1 = min(max(x1, 0), WW - 1);
        y0 = min(max(y0, 0), HH - 1);
        y1 = min(max(y1, 0), HH - 1);

        const float x0f = (float)x0, x1f = (float)x1;
        const float y0f = (float)y0, y1f = (float)y1;
        wa[bb] = (x1f - x) * (y1f - y);
        wb[bb] = (x1f - x) * (y - y0f);
        wc[bb] = (x - x0f) * (y1f - y);
        wd[bb] = (x - x0f) * (y - y0f);

        // Row-pair gather: 6 contiguous floats per row from xs = min(x0, W-2).
        const int xs = min(x0, WW - 2);
        hi_a[bb] = (x0 > xs);
        hi_c[bb] = (x1 > xs);

        const float* img = image + (size_t)(b0 + bb) * NN * CC;
        const float* rowA = img + ((size_t)y0 * WW + xs) * CC;
        const float* rowB = img + ((size_t)y1 * WW + xs) * CC;
        ISSUE_ROW(a4[bb], a2[bb], rowA);
        ISSUE_ROW(b4[bb], b2[bb], rowB);
    }

    // Phase B: counted waits + combine + store (batch bb waits only for its
    // own loads; later batches' loads remain in flight).
    float* __restrict__ o = out + (size_t)b0 * NN * CC + (size_t)n * CC;

    #define COMBINE(bb)                                                      \
    {                                                                        \
        const float la[6] = { a4[bb].x, a4[bb].y, a4[bb].z, a4[bb].w,        \
                              a2[bb].x, a2[bb].y };                          \
        const float lb[6] = { b4[bb].x, b4[bb].y, b4[bb].z, b4[bb].w,        \
                              b2[bb].x, b2[bb].y };                          \
        float res[CC];                                                       \
        _Pragma("unroll")                                                    \
        for (int c = 0; c < CC; ++c) {                                       \
            const float pa = hi_a[bb] ? la[c + 3] : la[c];                   \
            const float pc = hi_c[bb] ? la[c + 3] : la[c];                   \
            const float pb = hi_a[bb] ? lb[c + 3] : lb[c];                   \
            const float pd = hi_c[bb] ? lb[c + 3] : lb[c];                   \
            res[c] = wa[bb] * pa + wb[bb] * pb + wc[bb] * pc + wd[bb] * pd;  \
        }                                                                    \
        __builtin_memcpy(o + (size_t)(bb) * NN * CC, res, CC * sizeof(float)); \
    }

    WAIT_BATCH(12, a4[0], a2[0], b4[0], b2[0]);
    COMBINE(0);
    WAIT_BATCH(8, a4[1], a2[1], b4[1], b2[1]);
    COMBINE(1);
    WAIT_BATCH(4, a4[2], a2[2], b4[2], b2[2]);
    COMBINE(2);
    WAIT_BATCH(0, a4[3], a2[3], b4[3], b2[3]);
    COMBINE(3);
    #undef COMBINE
}

extern "C" void kernel_launch(void* const* d_in, const int* in_sizes, int n_in,
                              void* d_out, int out_size, void* d_ws, size_t ws_size,
                              hipStream_t stream) {
    const float* image        = (const float*)d_in[0];
    const float* dest_offsets = (const float*)d_in[1];
    const float* right_mat    = (const float*)d_in[2];
    const float* L_inv        = (const float*)d_in[3];
    const float* src_pts      = (const float*)d_in[4];
    float* out = (float*)d_out;

    dim3 grid(NN / 256, BB / BPB);
    dim3 block(256);
    hipLaunchKernelGGL(tps_kernel, grid, block, 0, stream,
                       image, dest_offsets, right_mat, L_inv, src_pts, out);
}

// Round 11
// 69.963 us; speedup vs baseline: 2.1495x; 1.3571x over previous
//
#include <hip/hip_runtime.h>

#define BB 32
#define HH 512
#define WW 512
#define CC 3
#define KK 16
#define NE 19          // K + 3
#define KNL 16         // nonlinear kernel terms (loaded from right_mat)
#define NN (HH * WW)   // 262144
#define BPB 4          // batches per block
#define NCOEFF (BPB * 2 * NE) // 152
// 2D output tiling: 32 wide x 8 tall per 256-thread block.
#define TLW 32
#define TLH 8
#define TILES_X (WW / TLW)  // 16
#define TILES_Y (HH / TLH)  // 64

__global__ __launch_bounds__(256, 4) void tps_kernel(
    const float* __restrict__ image,        // (B,H,W,C)
    const float* __restrict__ dest_offsets, // (B, 2K)
    const float* __restrict__ right_mat,    // (NE, N)
    const float* __restrict__ L_inv,        // (NE, NE)
    const float* __restrict__ src_pts,      // (2, K)
    float* __restrict__ out)                // (B,H,W,C)
{
    __shared__ float s_coeff[BPB][2][NE];
    const int tid = threadIdx.x;
    const int b0 = blockIdx.y * BPB;

    // TPS coefficients for this block's batch group:
    // coeff[bb][p][e] = sum_k (src[p][k] + off[b][p*K+k]) * L_inv[e][3+k]
    if (tid < NCOEFF) {
        const int bb = tid / (2 * NE);
        const int rem = tid - bb * (2 * NE);
        const int p = rem / NE;
        const int e = rem - p * NE;
        const int b = b0 + bb;
        float acc = 0.0f;
        #pragma unroll
        for (int k = 0; k < KK; ++k) {
            const float d = src_pts[p * KK + k] + dest_offsets[b * 2 * KK + p * KK + k];
            acc = fmaf(d, L_inv[e * NE + 3 + k], acc);
        }
        s_coeff[bb][p][e] = acc;
    }
    __syncthreads();

    // 2D tile -> pixel: vertical y0/y1 gather reuse stays inside the block
    // (L1) instead of spanning blocks on different XCDs.
    const int tix = blockIdx.x & (TILES_X - 1);
    const int tiy = blockIdx.x >> 4;
    const int col = tix * TLW + (tid & (TLW - 1));
    const int row = tiy * TLH + (tid >> 5);
    const int n = row * WW + col;

    // Linear right_mat rows [1; x_t; y_t]: computed (verified r5-r7).
    const float xt = fmaf((float)col, 2.0f / 511.0f, -1.0f);
    const float yt = fmaf((float)row, 2.0f / 511.0f, -1.0f);

    // Nonlinear rows: MUST be the exact precomputed values (r10 lesson:
    // recomputing with logf flips pixels across the trunc/clip
    // discontinuity at the image border -> absmax blowup).
    float rm[KNL];
    #pragma unroll
    for (int e = 0; e < KNL; ++e)
        rm[e] = right_mat[(size_t)(e + 3) * NN + n];

    float* __restrict__ o = out + (size_t)b0 * NN * CC + (size_t)n * CC;

    #pragma unroll
    for (int bb = 0; bb < BPB; ++bb) {
        const float* cf0 = s_coeff[bb][0];
        const float* cf1 = s_coeff[bb][1];
        float tx = fmaf(cf0[1], xt, cf0[0]);
        float ty = fmaf(cf1[1], xt, cf1[0]);
        tx = fmaf(cf0[2], yt, tx);
        ty = fmaf(cf1[2], yt, ty);
        #pragma unroll
        for (int k = 0; k < KNL; ++k) {
            tx = fmaf(cf0[3 + k], rm[k], tx);
            ty = fmaf(cf1[3 + k], rm[k], ty);
        }

        const float x = 0.5f * (tx + 1.0f) * (float)WW;
        const float y = 0.5f * (ty + 1.0f) * (float)HH;

        int x0 = (int)x;   // trunc toward zero, matches astype(int32)
        int x1 = x0 + 1;
        int y0 = (int)y;
        int y1 = y0 + 1;
        x0 = min(max(x0, 0), WW - 1);
        x1 = min(max(x1, 0), WW - 1);
        y0 = min(max(y0, 0), HH - 1);
        y1 = min(max(y1, 0), HH - 1);

        const float x0f = (float)x0, x1f = (float)x1;
        const float y0f = (float)y0, y1f = (float)y1;
        const float wa = (x1f - x) * (y1f - y);
        const float wb = (x1f - x) * (y - y0f);
        const float wc = (x - x0f) * (y1f - y);
        const float wd = (x - x0f) * (y - y0f);

        // Row-pair gather: 6 contiguous floats per row from xs = min(x0, W-2).
        const int xs = min(x0, WW - 2);
        const bool hi_a = (x0 > xs);
        const bool hi_c = (x1 > xs);

        const float* img = image + (size_t)(b0 + bb) * NN * CC;
        const float* rowA = img + ((size_t)y0 * WW + xs) * CC;
        const float* rowB = img + ((size_t)y1 * WW + xs) * CC;
        float la[6], lb[6];
        __builtin_memcpy(la, rowA, 6 * sizeof(float));
        __builtin_memcpy(lb, rowB, 6 * sizeof(float));

        float res[CC];
        #pragma unroll
        for (int c = 0; c < CC; ++c) {
            const float pa = hi_a ? la[c + 3] : la[c];
            const float pc = hi_c ? la[c + 3] : la[c];
            const float pb = hi_a ? lb[c + 3] : lb[c];
            const float pd = hi_c ? lb[c + 3] : lb[c];
            res[c] = wa * pa + wb * pb + wc * pc + wd * pd;
        }
        __builtin_memcpy(o + (size_t)bb * NN * CC, res, CC * sizeof(float));
    }
}

extern "C" void kernel_launch(void* const* d_in, const int* in_sizes, int n_in,
                              void* d_out, int out_size, void* d_ws, size_t ws_size,
                              hipStream_t stream) {
    const float* image        = (const float*)d_in[0];
    const float* dest_offsets = (const float*)d_in[1];
    const float* right_mat    = (const float*)d_in[2];
    const float* L_inv        = (const float*)d_in[3];
    const float* src_pts      = (const float*)d_in[4];
    float* out = (float*)d_out;

    dim3 grid(TILES_X * TILES_Y, BB / BPB);
    dim3 block(256);
    hipLaunchKernelGGL(tps_kernel, grid, block, 0, stream,
                       image, dest_offsets, right_mat, L_inv, src_pts, out);
}

// Round 12
// 66.125 us; speedup vs baseline: 2.2742x; 1.0580x over previous
//
#include <hip/hip_runtime.h>

#define BB 32
#define HH 512
#define WW 512
#define CC 3
#define KK 16
#define NE 19          // K + 3
#define KNL 16         // nonlinear kernel terms (loaded from right_mat)
#define NN (HH * WW)   // 262144
#define BPB 8          // batches per block
#define NCOEFF (BPB * 2 * NE) // 304
// 2D output tiling: 32 wide x 8 tall per 256-thread block.
#define TLW 32
#define TLH 8
#define TILES_X (WW / TLW)  // 16
#define TILES_Y (HH / TLH)  // 64

__global__ __launch_bounds__(256, 4) void tps_kernel(
    const float* __restrict__ image,        // (B,H,W,C)
    const float* __restrict__ dest_offsets, // (B, 2K)
    const float* __restrict__ right_mat,    // (NE, N)
    const float* __restrict__ L_inv,        // (NE, NE)
    const float* __restrict__ src_pts,      // (2, K)
    float* __restrict__ out)                // (B,H,W,C)
{
    __shared__ float s_coeff[BPB][2][NE];
    const int tid = threadIdx.x;
    const int b0 = blockIdx.y * BPB;

    // TPS coefficients for this block's batch group:
    // coeff[bb][p][e] = sum_k (src[p][k] + off[b][p*K+k]) * L_inv[e][3+k]
    for (int i = tid; i < NCOEFF; i += 256) {
        const int bb = i / (2 * NE);
        const int rem = i - bb * (2 * NE);
        const int p = rem / NE;
        const int e = rem - p * NE;
        const int b = b0 + bb;
        float acc = 0.0f;
        #pragma unroll
        for (int k = 0; k < KK; ++k) {
            const float d = src_pts[p * KK + k] + dest_offsets[b * 2 * KK + p * KK + k];
            acc = fmaf(d, L_inv[e * NE + 3 + k], acc);
        }
        ((float*)s_coeff)[i] = acc;
    }
    __syncthreads();

    // 2D tile -> pixel: vertical y0/y1 gather reuse stays inside the block
    // (L1) instead of spanning blocks on different XCDs.
    const int tix = blockIdx.x & (TILES_X - 1);
    const int tiy = blockIdx.x >> 4;
    const int col = tix * TLW + (tid & (TLW - 1));
    const int row = tiy * TLH + (tid >> 5);
    const int n = row * WW + col;

    // Linear right_mat rows [1; x_t; y_t]: computed (verified r5-r7, r11).
    const float xt = fmaf((float)col, 2.0f / 511.0f, -1.0f);
    const float yt = fmaf((float)row, 2.0f / 511.0f, -1.0f);

    // Nonlinear rows: MUST be the exact precomputed values (r10 lesson:
    // recomputing with logf flips pixels across the trunc/clip
    // discontinuity at the image border -> absmax blowup).
    float rm[KNL];
    #pragma unroll
    for (int e = 0; e < KNL; ++e)
        rm[e] = right_mat[(size_t)(e + 3) * NN + n];

    float* __restrict__ o = out + (size_t)b0 * NN * CC + (size_t)n * CC;

    #pragma unroll
    for (int bb = 0; bb < BPB; ++bb) {
        const float* cf0 = s_coeff[bb][0];
        const float* cf1 = s_coeff[bb][1];
        float tx = fmaf(cf0[1], xt, cf0[0]);
        float ty = fmaf(cf1[1], xt, cf1[0]);
        tx = fmaf(cf0[2], yt, tx);
        ty = fmaf(cf1[2], yt, ty);
        #pragma unroll
        for (int k = 0; k < KNL; ++k) {
            tx = fmaf(cf0[3 + k], rm[k], tx);
            ty = fmaf(cf1[3 + k], rm[k], ty);
        }

        const float x = 0.5f * (tx + 1.0f) * (float)WW;
        const float y = 0.5f * (ty + 1.0f) * (float)HH;

        int x0 = (int)x;   // trunc toward zero, matches astype(int32)
        int x1 = x0 + 1;
        int y0 = (int)y;
        int y1 = y0 + 1;
        x0 = min(max(x0, 0), WW - 1);
        x1 = min(max(x1, 0), WW - 1);
        y0 = min(max(y0, 0), HH - 1);
        y1 = min(max(y1, 0), HH - 1);

        const float x0f = (float)x0, x1f = (float)x1;
        const float y0f = (float)y0, y1f = (float)y1;
        const float wa = (x1f - x) * (y1f - y);
        const float wb = (x1f - x) * (y - y0f);
        const float wc = (x - x0f) * (y1f - y);
        const float wd = (x - x0f) * (y - y0f);

        // Row-pair gather: 6 contiguous floats per row from xs = min(x0, W-2).
        const int xs = min(x0, WW - 2);
        const bool hi_a = (x0 > xs);
        const bool hi_c = (x1 > xs);

        const float* img = image + (size_t)(b0 + bb) * NN * CC;
        const float* rowA = img + ((size_t)y0 * WW + xs) * CC;
        const float* rowB = img + ((size_t)y1 * WW + xs) * CC;
        float la[6], lb[6];
        __builtin_memcpy(la, rowA, 6 * sizeof(float));
        __builtin_memcpy(lb, rowB, 6 * sizeof(float));

        float res[CC];
        #pragma unroll
        for (int c = 0; c < CC; ++c) {
            const float pa = hi_a ? la[c + 3] : la[c];
            const float pc = hi_c ? la[c + 3] : la[c];
            const float pb = hi_a ? lb[c + 3] : lb[c];
            const float pd = hi_c ? lb[c + 3] : lb[c];
            res[c] = wa * pa + wb * pb + wc * pc + wd * pd;
        }
        __builtin_memcpy(o + (size_t)bb * NN * CC, res, CC * sizeof(float));
    }
}

extern "C" void kernel_launch(void* const* d_in, const int* in_sizes, int n_in,
                              void* d_out, int out_size, void* d_ws, size_t ws_size,
                              hipStream_t stream) {
    const float* image        = (const float*)d_in[0];
    const float* dest_offsets = (const float*)d_in[1];
    const float* right_mat    = (const float*)d_in[2];
    const float* L_inv        = (const float*)d_in[3];
    const float* src_pts      = (const float*)d_in[4];
    float* out = (float*)d_out;

    dim3 grid(TILES_X * TILES_Y, BB / BPB);
    dim3 block(256);
    hipLaunchKernelGGL(tps_kernel, grid, block, 0, stream,
                       image, dest_offsets, right_mat, L_inv, src_pts, out);
}

// Round 13
// 65.122 us; speedup vs baseline: 2.3093x; 1.0154x over previous
//
#include <hip/hip_runtime.h>

#define BB 32
#define HH 512
#define WW 512
#define CC 3
#define KK 16
#define NE 19          // K + 3
#define KNL 16         // nonlinear kernel terms (loaded from right_mat)
#define NN (HH * WW)   // 262144
#define BPB 16         // batches per block
#define NCOEFF (BPB * 2 * NE) // 608
// 2D output tiling: 32 wide x 8 tall per 256-thread block.
#define TLW 32
#define TLH 8
#define TILES_X (WW / TLW)  // 16
#define TILES_Y (HH / TLH)  // 64

__global__ __launch_bounds__(256, 4) void tps_kernel(
    const float* __restrict__ image,        // (B,H,W,C)
    const float* __restrict__ dest_offsets, // (B, 2K)
    const float* __restrict__ right_mat,    // (NE, N)
    const float* __restrict__ L_inv,        // (NE, NE)
    const float* __restrict__ src_pts,      // (2, K)
    float* __restrict__ out)                // (B,H,W,C)
{
    __shared__ float s_coeff[BPB][2][NE];
    const int tid = threadIdx.x;
    const int b0 = blockIdx.y * BPB;

    // TPS coefficients for this block's batch group:
    // coeff[bb][p][e] = sum_k (src[p][k] + off[b][p*K+k]) * L_inv[e][3+k]
    for (int i = tid; i < NCOEFF; i += 256) {
        const int bb = i / (2 * NE);
        const int rem = i - bb * (2 * NE);
        const int p = rem / NE;
        const int e = rem - p * NE;
        const int b = b0 + bb;
        float acc = 0.0f;
        #pragma unroll
        for (int k = 0; k < KK; ++k) {
            const float d = src_pts[p * KK + k] + dest_offsets[b * 2 * KK + p * KK + k];
            acc = fmaf(d, L_inv[e * NE + 3 + k], acc);
        }
        ((float*)s_coeff)[i] = acc;
    }
    __syncthreads();

    // 2D tile -> pixel: vertical y0/y1 gather reuse stays inside the block
    // (L1) instead of spanning blocks on different XCDs.
    const int tix = blockIdx.x & (TILES_X - 1);
    const int tiy = blockIdx.x >> 4;
    const int col = tix * TLW + (tid & (TLW - 1));
    const int row = tiy * TLH + (tid >> 5);
    const int n = row * WW + col;

    // Linear right_mat rows [1; x_t; y_t]: computed (verified r5-r7, r11-r12).
    const float xt = fmaf((float)col, 2.0f / 511.0f, -1.0f);
    const float yt = fmaf((float)row, 2.0f / 511.0f, -1.0f);

    // Nonlinear rows: MUST be the exact precomputed values (r10 lesson:
    // recomputing with logf flips pixels across the trunc/clip
    // discontinuity at the image border -> absmax blowup).
    float rm[KNL];
    #pragma unroll
    for (int e = 0; e < KNL; ++e)
        rm[e] = right_mat[(size_t)(e + 3) * NN + n];

    float* __restrict__ o = out + (size_t)b0 * NN * CC + (size_t)n * CC;

    #pragma unroll
    for (int bb = 0; bb < BPB; ++bb) {
        const float* cf0 = s_coeff[bb][0];
        const float* cf1 = s_coeff[bb][1];
        float tx = fmaf(cf0[1], xt, cf0[0]);
        float ty = fmaf(cf1[1], xt, cf1[0]);
        tx = fmaf(cf0[2], yt, tx);
        ty = fmaf(cf1[2], yt, ty);
        #pragma unroll
        for (int k = 0; k < KNL; ++k) {
            tx = fmaf(cf0[3 + k], rm[k], tx);
            ty = fmaf(cf1[3 + k], rm[k], ty);
        }

        const float x = 0.5f * (tx + 1.0f) * (float)WW;
        const float y = 0.5f * (ty + 1.0f) * (float)HH;

        int x0 = (int)x;   // trunc toward zero, matches astype(int32)
        int x1 = x0 + 1;
        int y0 = (int)y;
        int y1 = y0 + 1;
        x0 = min(max(x0, 0), WW - 1);
        x1 = min(max(x1, 0), WW - 1);
        y0 = min(max(y0, 0), HH - 1);
        y1 = min(max(y1, 0), HH - 1);

        const float x0f = (float)x0, x1f = (float)x1;
        const float y0f = (float)y0, y1f = (float)y1;
        const float wa = (x1f - x) * (y1f - y);
        const float wb = (x1f - x) * (y - y0f);
        const float wc = (x - x0f) * (y1f - y);
        const float wd = (x - x0f) * (y - y0f);

        // Row-pair gather: 6 contiguous floats per row from xs = min(x0, W-2).
        const int xs = min(x0, WW - 2);
        const bool hi_a = (x0 > xs);
        const bool hi_c = (x1 > xs);

        const float* img = image + (size_t)(b0 + bb) * NN * CC;
        const float* rowA = img + ((size_t)y0 * WW + xs) * CC;
        const float* rowB = img + ((size_t)y1 * WW + xs) * CC;
        float la[6], lb[6];
        __builtin_memcpy(la, rowA, 6 * sizeof(float));
        __builtin_memcpy(lb, rowB, 6 * sizeof(float));

        float res[CC];
        #pragma unroll
        for (int c = 0; c < CC; ++c) {
            const float pa = hi_a ? la[c + 3] : la[c];
            const float pc = hi_c ? la[c + 3] : la[c];
            const float pb = hi_a ? lb[c + 3] : lb[c];
            const float pd = hi_c ? lb[c + 3] : lb[c];
            res[c] = wa * pa + wb * pb + wc * pc + wd * pd;
        }
        __builtin_memcpy(o + (size_t)bb * NN * CC, res, CC * sizeof(float));
    }
}

extern "C" void kernel_launch(void* const* d_in, const int* in_sizes, int n_in,
                              void* d_out, int out_size, void* d_ws, size_t ws_size,
                              hipStream_t stream) {
    const float* image        = (const float*)d_in[0];
    const float* dest_offsets = (const float*)d_in[1];
    const float* right_mat    = (const float*)d_in[2];
    const float* L_inv        = (const float*)d_in[3];
    const float* src_pts      = (const float*)d_in[4];
    float* out = (float*)d_out;

    dim3 grid(TILES_X * TILES_Y, BB / BPB);
    dim3 block(256);
    hipLaunchKernelGGL(tps_kernel, grid, block, 0, stream,
                       image, dest_offsets, right_mat, L_inv, src_pts, out);
}